// Round 5
// baseline (180.420 us; speedup 1.0000x reference)
//
#include <hip/hip_runtime.h>
#include <hip/hip_bf16.h>
#include <stdint.h>

typedef __attribute__((ext_vector_type(8))) short bf16x8;
typedef __attribute__((ext_vector_type(4))) float f32x4;
typedef __attribute__((ext_vector_type(4))) unsigned int u32x4;
typedef __attribute__((ext_vector_type(2))) unsigned int u32x2;
typedef unsigned short u16;
typedef unsigned int u32;

#define N_NODES 8192
#define N_EDGES 1024
#define F_DIM   256

__device__ __forceinline__ u16 f2bf(float f) {           // round-nearest-even
    union { float f; u32 u; } v; v.f = f;
    u32 u = v.u;
    u = (u + 0x7FFFu + ((u >> 16) & 1u)) >> 16;
    return (u16)u;
}
// truncation pack: exact for binary H (1.0 -> 0x3F80, 0.0 -> 0x0000)
__device__ __forceinline__ u32 packtrunc(float a, float b) {
    union { float f; u32 u; } x, y; x.f = a; y.f = b;
    return (x.u >> 16) | (y.u & 0xFFFF0000u);
}

// ---------------------------------------------------------------------------
// prep_h: one pass over H [8192 x 1024] fp32.
//   - Ht [1024 x 8192] bf16 (transposed, A-operand of GEMM1), 16B stores
//   - dv[8192] row sums, de[1024] col sums (exact: sums of 0/1)
// GEMM2 reads H fp32 directly (row-major is already its A layout).
// 64x64 tile / block, 256 threads, grid (16, 128).
// ---------------------------------------------------------------------------
__global__ void prep_h(const float* __restrict__ H, u16* __restrict__ Ht,
                       float* __restrict__ dv, float* __restrict__ de) {
    __shared__ u16 tT[64 * 72];
    __shared__ float dv_s[64];
    __shared__ float de_s[64];
    const int tid = threadIdx.x;
    if (tid < 64) { dv_s[tid] = 0.f; de_s[tid] = 0.f; }
    __syncthreads();
    const int r0 = blockIdx.y * 64;
    const int c0 = blockIdx.x * 64;
    const int lr = tid >> 4;
    const int lc = (tid & 15) * 4;
    float cs0 = 0.f, cs1 = 0.f, cs2 = 0.f, cs3 = 0.f;
#pragma unroll
    for (int i = 0; i < 4; i++) {
        const int row = r0 + lr + i * 16;
        f32x4 v = *(const f32x4*)(&H[(size_t)row * N_EDGES + c0 + lc]);
        atomicAdd(&dv_s[lr + i * 16], v[0] + v[1] + v[2] + v[3]);
        cs0 += v[0]; cs1 += v[1]; cs2 += v[2]; cs3 += v[3];
        // binary -> truncation is exact
        union { float f; u32 u; } b0, b1, b2, b3;
        b0.f = v[0]; b1.f = v[1]; b2.f = v[2]; b3.f = v[3];
        tT[(lc + 0) * 72 + lr + i * 16] = (u16)(b0.u >> 16);
        tT[(lc + 1) * 72 + lr + i * 16] = (u16)(b1.u >> 16);
        tT[(lc + 2) * 72 + lr + i * 16] = (u16)(b2.u >> 16);
        tT[(lc + 3) * 72 + lr + i * 16] = (u16)(b3.u >> 16);
    }
    atomicAdd(&de_s[lc + 0], cs0);
    atomicAdd(&de_s[lc + 1], cs1);
    atomicAdd(&de_s[lc + 2], cs2);
    atomicAdd(&de_s[lc + 3], cs3);
    __syncthreads();
    if (tid < 64) {
        atomicAdd(&dv[r0 + tid], dv_s[tid]);
        atomicAdd(&de[c0 + tid], de_s[tid]);
    }
    const int er = tid >> 2;          // 0..63
    const int ch = (tid & 3) * 8;
#pragma unroll
    for (int half = 0; half < 2; half++) {
        const int c = ch + half * 32;
        u32x4 v = *(const u32x4*)(&tT[er * 72 + c]);
        *(u32x4*)(&Ht[(size_t)(c0 + er) * N_NODES + r0 + c]) = v;
    }
}

// ---------------------------------------------------------------------------
// prep_x: Xst[f][n] = bf16(X[n][f] * rsqrt(dv[n]))  -> [256 x 8192]
// ---------------------------------------------------------------------------
__global__ void prep_x(const float* __restrict__ X, const float* __restrict__ dv,
                       u16* __restrict__ Xst) {
    __shared__ u16 tT[64 * 72];
    const int tid = threadIdx.x;
    const int r0 = blockIdx.y * 64;
    const int c0 = blockIdx.x * 64;
    const int lr = tid >> 4;
    const int lc = (tid & 15) * 4;
#pragma unroll
    for (int i = 0; i < 4; i++) {
        const int row = r0 + lr + i * 16;
        const float s = rsqrtf(dv[row]);
        f32x4 v = *(const f32x4*)(&X[(size_t)row * F_DIM + c0 + lc]);
        tT[(lc + 0) * 72 + lr + i * 16] = f2bf(v[0] * s);
        tT[(lc + 1) * 72 + lr + i * 16] = f2bf(v[1] * s);
        tT[(lc + 2) * 72 + lr + i * 16] = f2bf(v[2] * s);
        tT[(lc + 3) * 72 + lr + i * 16] = f2bf(v[3] * s);
    }
    __syncthreads();
    const int er = tid >> 2;
    const int ch = (tid & 3) * 8;
#pragma unroll
    for (int half = 0; half < 2; half++) {
        const int c = ch + half * 32;
        u32x4 v = *(const u32x4*)(&tT[er * 72 + c]);
        *(u32x4*)(&Xst[(size_t)(c0 + er) * N_NODES + r0 + c]) = v;
    }
}

// ---------------------------------------------------------------------------
// gemm64: C[M x N] = A[M x K] * Bt[N x K]^T, bf16 MFMA, fp32 accumulate.
// 64x64 tile / block, 256 threads (4 waves 2x2, wave tile 32x32), BK=64.
// LDS row stride 72 u16 (144 B): 16B-aligned, 2-way bank aliasing only.
// The measured-best structure (R1/R3); do not restructure.
// AMODE 0: A is bf16            AMODE 1: A is fp32, truncation-cast (H)
// EPI 0: fp32 partial store at outF + blockIdx.z*pstride  (GEMM1 split-K)
// EPI 1: fp32 out = v*rsqrt(rowScale[row]) + bias[col]    (GEMM2 final)
// ---------------------------------------------------------------------------
template <int AMODE, int EPI>
__global__ __launch_bounds__(256, 4)
void gemm64(const u16* __restrict__ A16, const float* __restrict__ A32,
            const u16* __restrict__ Bt, int lda, int ldb, int kSplit,
            float* __restrict__ outF, int ldc, int pstride,
            const float* __restrict__ rowScale,
            const float* __restrict__ bias) {
    __shared__ u16 As[64 * 72];
    __shared__ u16 Bs[64 * 72];
    const int tid = threadIdx.x;
    const int lane = tid & 63;
    const int wave = tid >> 6;
    const int wm = wave >> 1, wn = wave & 1;
    const int row16 = lane & 15;
    const int quad = lane >> 4;

    const int row0 = blockIdx.y * 64;
    const int col0 = blockIdx.x * 64;
    const int k0 = blockIdx.z * kSplit;
    const int k1 = k0 + kSplit;

    const int sr = tid >> 2;            // 0..63
    const int sk = (tid & 3) * 16;      // u16 units: 0,16,32,48

    const u16*   gA16 = A16 + (size_t)(row0 + sr) * lda + sk;
    const float* gA32 = A32 + (size_t)(row0 + sr) * lda + sk;
    const u16*   gB   = Bt + (size_t)(col0 + sr) * ldb + sk;

    f32x4 acc[2][2] = {};

    for (int k = k0; k < k1; k += 64) {
        u32x4 a0, a1;
        if (AMODE == 0) {
            a0 = *(const u32x4*)(gA16 + k + 0);
            a1 = *(const u32x4*)(gA16 + k + 8);
        } else {
            f32x4 f0 = *(const f32x4*)(gA32 + k + 0);
            f32x4 f1 = *(const f32x4*)(gA32 + k + 4);
            f32x4 f2 = *(const f32x4*)(gA32 + k + 8);
            f32x4 f3 = *(const f32x4*)(gA32 + k + 12);
            a0[0] = packtrunc(f0[0], f0[1]); a0[1] = packtrunc(f0[2], f0[3]);
            a0[2] = packtrunc(f1[0], f1[1]); a0[3] = packtrunc(f1[2], f1[3]);
            a1[0] = packtrunc(f2[0], f2[1]); a1[1] = packtrunc(f2[2], f2[3]);
            a1[2] = packtrunc(f3[0], f3[1]); a1[3] = packtrunc(f3[2], f3[3]);
        }
        u32x4 b0 = *(const u32x4*)(gB + k + 0);
        u32x4 b1 = *(const u32x4*)(gB + k + 8);
        *(u32x4*)(&As[sr * 72 + sk + 0]) = a0;
        *(u32x4*)(&As[sr * 72 + sk + 8]) = a1;
        *(u32x4*)(&Bs[sr * 72 + sk + 0]) = b0;
        *(u32x4*)(&Bs[sr * 72 + sk + 8]) = b1;
        __syncthreads();
#pragma unroll
        for (int ks = 0; ks < 2; ks++) {
            bf16x8 af[2], bfr[2];
#pragma unroll
            for (int i = 0; i < 2; i++)
                af[i] = *(const bf16x8*)(&As[(wm * 32 + i * 16 + row16) * 72 + ks * 32 + quad * 8]);
#pragma unroll
            for (int j = 0; j < 2; j++)
                bfr[j] = *(const bf16x8*)(&Bs[(wn * 32 + j * 16 + row16) * 72 + ks * 32 + quad * 8]);
#pragma unroll
            for (int i = 0; i < 2; i++)
#pragma unroll
                for (int j = 0; j < 2; j++)
                    acc[i][j] = __builtin_amdgcn_mfma_f32_16x16x32_bf16(
                        af[i], bfr[j], acc[i][j], 0, 0, 0);
        }
        __syncthreads();
    }

    float* o = outF + (size_t)blockIdx.z * pstride;
#pragma unroll
    for (int i = 0; i < 2; i++) {
#pragma unroll
        for (int j = 0; j < 2; j++) {
            const int col = col0 + wn * 32 + j * 16 + row16;
#pragma unroll
            for (int r = 0; r < 4; r++) {
                const int row = row0 + wm * 32 + i * 16 + quad * 4 + r;
                float v = acc[i][j][r];
                if (EPI == 0) {
                    o[(size_t)row * ldc + col] = v;
                } else {
                    o[(size_t)row * ldc + col] = v * rsqrtf(rowScale[row]) + bias[col];
                }
            }
        }
    }
}

// ---------------------------------------------------------------------------
// gemm_we: M2t[j][e] = sum_f W[j][f] * (sum_p Metp[p][e][f]) / de[e]  (bf16)
// Fuses split-K reduction (P=8 partials) + De^-1 + fp32->bf16 + W-GEMM.
// Tile 64(j) x 64(e), grid (16, 4), 256 threads, BK=64, K=256.
// ---------------------------------------------------------------------------
__global__ __launch_bounds__(256)
void gemm_we(const float* __restrict__ W, const float* __restrict__ Met,
             const float* __restrict__ de, u16* __restrict__ M2t) {
    __shared__ u16 As[64 * 72];
    __shared__ u16 Bs[64 * 72];
    const int tid = threadIdx.x;
    const int lane = tid & 63;
    const int wave = tid >> 6;
    const int wm = wave >> 1, wn = wave & 1;
    const int row16 = lane & 15;
    const int quad = lane >> 4;

    const int j0 = blockIdx.y * 64;
    const int e0 = blockIdx.x * 64;

    const int sr = tid >> 2;
    const int fb = (tid & 3) * 16;

    const float dei = 1.0f / de[e0 + sr];

    f32x4 acc[2][2] = {};

    for (int k = 0; k < 256; k += 64) {
#pragma unroll
        for (int s = 0; s < 4; s++) {
            f32x4 w = *(const f32x4*)(&W[(size_t)(j0 + sr) * 256 + k + fb + s * 4]);
            u32x2 pk;
            pk[0] = (u32)f2bf(w[0]) | ((u32)f2bf(w[1]) << 16);
            pk[1] = (u32)f2bf(w[2]) | ((u32)f2bf(w[3]) << 16);
            *(u32x2*)(&As[sr * 72 + fb + s * 4]) = pk;
        }
#pragma unroll
        for (int s = 0; s < 4; s++) {
            f32x4 m = {0.f, 0.f, 0.f, 0.f};
#pragma unroll
            for (int p = 0; p < 8; p++) {
                f32x4 mp = *(const f32x4*)(&Met[(size_t)p * (N_EDGES * F_DIM)
                                               + (size_t)(e0 + sr) * 256 + k + fb + s * 4]);
                m[0] += mp[0]; m[1] += mp[1]; m[2] += mp[2]; m[3] += mp[3];
            }
            u32x2 pk;
            pk[0] = (u32)f2bf(m[0] * dei) | ((u32)f2bf(m[1] * dei) << 16);
            pk[1] = (u32)f2bf(m[2] * dei) | ((u32)f2bf(m[3] * dei) << 16);
            *(u32x2*)(&Bs[sr * 72 + fb + s * 4]) = pk;
        }
        __syncthreads();
#pragma unroll
        for (int ks = 0; ks < 2; ks++) {
            bf16x8 af[2], bfr[2];
#pragma unroll
            for (int i = 0; i < 2; i++)
                af[i] = *(const bf16x8*)(&As[(wm * 32 + i * 16 + row16) * 72 + ks * 32 + quad * 8]);
#pragma unroll
            for (int j = 0; j < 2; j++)
                bfr[j] = *(const bf16x8*)(&Bs[(wn * 32 + j * 16 + row16) * 72 + ks * 32 + quad * 8]);
#pragma unroll
            for (int i = 0; i < 2; i++)
#pragma unroll
                for (int j = 0; j < 2; j++)
                    acc[i][j] = __builtin_amdgcn_mfma_f32_16x16x32_bf16(
                        af[i], bfr[j], acc[i][j], 0, 0, 0);
        }
        __syncthreads();
    }

#pragma unroll
    for (int i = 0; i < 2; i++) {
#pragma unroll
        for (int j = 0; j < 2; j++) {
            const int col = e0 + wn * 32 + j * 16 + row16;
#pragma unroll
            for (int r = 0; r < 4; r++) {
                const int row = j0 + wm * 32 + i * 16 + quad * 4 + r;
                M2t[(size_t)row * N_EDGES + col] = f2bf(acc[i][j][r]);
            }
        }
    }
}

// ---------------------------------------------------------------------------
extern "C" void kernel_launch(void* const* d_in, const int* in_sizes, int n_in,
                              void* d_out, int out_size, void* d_ws, size_t ws_size,
                              hipStream_t stream) {
    (void)in_sizes; (void)n_in; (void)out_size; (void)ws_size;
    const float* X = (const float*)d_in[0];   // [8192 x 256]
    const float* H = (const float*)d_in[1];   // [8192 x 1024]
    const float* W = (const float*)d_in[2];   // [256 x 256]
    const float* b = (const float*)d_in[3];   // [256]
    float* out = (float*)d_out;               // [8192 x 256] fp32

    char* ws = (char*)d_ws;
    float* dv   = (float*)(ws);                // 32 KB
    float* de   = (float*)(ws + 0x8000);       // 4 KB
    float* Macc = (float*)(ws + 0x10000);      // 8 MB: 8 x [1024 x 256] fp32
    u16*   Ht   = (u16*)(ws + 0x810000);       // 16 MB [1024 x 8192]
    u16*   Xst  = (u16*)(ws + 0x1810000);      // 4 MB  [256 x 8192]
    u16*   M2t  = (u16*)(ws + 0x1C10000);      // 512 KB [256 x 1024]

    hipMemsetAsync(ws, 0, 0x9000, stream);     // dv + de

    prep_h<<<dim3(16, 128), 256, 0, stream>>>(H, Ht, dv, de);
    prep_x<<<dim3(4, 128), 256, 0, stream>>>(X, dv, Xst);

    // GEMM1: Met_p[e][f]; M=1024(e), N=256(f), K=8192(n), split-K=8.
    // A=Ht bf16, Bt=Xst. grid (4,16,8)=512 blocks of 256 thr (R1's best shape).
    gemm64<0, 0><<<dim3(4, 16, 8), 256, 0, stream>>>(
        Ht, nullptr, Xst, 8192, 8192, 1024, Macc, 256, N_EDGES * F_DIM,
        nullptr, nullptr);

    // fused: reduce 8 partials + De^-1 + W-GEMM -> M2t[j][e] bf16 [256 x 1024]
    gemm_we<<<dim3(16, 4), 256, 0, stream>>>(W, Macc, de, M2t);

    // GEMM2: out[n][j] = rsqrt(dv[n]) * sum_e H[n][e]*M2t[j][e] + b[j]
    // A=H fp32 (read once, truncation-cast), Bt=M2t (L2-resident).
    // M=8192(n), N=256(j), K=1024(e). grid (4,128)=512 blocks.
    gemm64<1, 1><<<dim3(4, 128, 1), 256, 0, stream>>>(
        nullptr, H, M2t, 1024, 1024, 1024, out, 256, 0, dv, b);
}

// Round 6
// 154.046 us; speedup vs baseline: 1.1712x; 1.1712x over previous
//
#include <hip/hip_runtime.h>
#include <hip/hip_bf16.h>
#include <stdint.h>

typedef __attribute__((ext_vector_type(8))) short bf16x8;
typedef __attribute__((ext_vector_type(4))) float f32x4;
typedef __attribute__((ext_vector_type(4))) unsigned int u32x4;
typedef __attribute__((ext_vector_type(2))) unsigned int u32x2;
typedef unsigned short u16;
typedef unsigned int u32;

#define N_NODES 8192
#define N_EDGES 1024
#define F_DIM   256

__device__ __forceinline__ u16 f2bf(float f) {
    union { float f; u32 u; } v; v.f = f;
    u32 u = v.u;
    u = (u + 0x7FFFu + ((u >> 16) & 1u)) >> 16;   // round-nearest-even
    return (u16)u;
}

// ---------------------------------------------------------------------------
// prep_h — R1 verbatim (the 161 µs build).
// One pass over H [8192 x 1024] fp32:
//   - Hb [8192 x 1024] bf16 (row-major, A-operand of GEMM2)
//   - Ht [1024 x 8192] bf16 (transposed via LDS, Bt-operand of GEMM1)
//   - dv[8192] row sums, de[1024] col sums (exact: sums of 0/1)
// ---------------------------------------------------------------------------
__global__ void prep_h(const float* __restrict__ H, u16* __restrict__ Hb,
                       u16* __restrict__ Ht, float* __restrict__ dv,
                       float* __restrict__ de) {
    __shared__ u16 tT[64 * 66];
    __shared__ float dv_s[64];
    __shared__ float de_s[64];
    const int tid = threadIdx.x;
    if (tid < 64) { dv_s[tid] = 0.f; de_s[tid] = 0.f; }
    __syncthreads();
    const int r0 = blockIdx.y * 64;
    const int c0 = blockIdx.x * 64;
    const int lr = tid >> 4;
    const int lc = (tid & 15) * 4;
    float cs0 = 0.f, cs1 = 0.f, cs2 = 0.f, cs3 = 0.f;
#pragma unroll
    for (int i = 0; i < 4; i++) {
        const int row = r0 + lr + i * 16;
        f32x4 v = *(const f32x4*)(&H[(size_t)row * N_EDGES + c0 + lc]);
        atomicAdd(&dv_s[lr + i * 16], v[0] + v[1] + v[2] + v[3]);
        cs0 += v[0]; cs1 += v[1]; cs2 += v[2]; cs3 += v[3];
        const u16 b0 = f2bf(v[0]), b1 = f2bf(v[1]), b2 = f2bf(v[2]), b3 = f2bf(v[3]);
        u32x2 pk; pk[0] = (u32)b0 | ((u32)b1 << 16); pk[1] = (u32)b2 | ((u32)b3 << 16);
        *(u32x2*)(&Hb[(size_t)row * N_EDGES + c0 + lc]) = pk;
        tT[(lc + 0) * 66 + lr + i * 16] = b0;
        tT[(lc + 1) * 66 + lr + i * 16] = b1;
        tT[(lc + 2) * 66 + lr + i * 16] = b2;
        tT[(lc + 3) * 66 + lr + i * 16] = b3;
    }
    atomicAdd(&de_s[lc + 0], cs0);
    atomicAdd(&de_s[lc + 1], cs1);
    atomicAdd(&de_s[lc + 2], cs2);
    atomicAdd(&de_s[lc + 3], cs3);
    __syncthreads();
    if (tid < 64) {
        atomicAdd(&dv[r0 + tid], dv_s[tid]);
        atomicAdd(&de[c0 + tid], de_s[tid]);
    }
#pragma unroll
    for (int i = 0; i < 4; i++) {
        const int er = lr + i * 16;
        const u16 b0 = tT[er * 66 + lc + 0];
        const u16 b1 = tT[er * 66 + lc + 1];
        const u16 b2 = tT[er * 66 + lc + 2];
        const u16 b3 = tT[er * 66 + lc + 3];
        u32x2 pk; pk[0] = (u32)b0 | ((u32)b1 << 16); pk[1] = (u32)b2 | ((u32)b3 << 16);
        *(u32x2*)(&Ht[(size_t)(c0 + er) * N_NODES + r0 + lc]) = pk;
    }
}

// ---------------------------------------------------------------------------
// prep_x — R1 verbatim. Xst[f][n] = bf16(X[n][f] * rsqrt(dv[n])) [256 x 8192]
// ---------------------------------------------------------------------------
__global__ void prep_x(const float* __restrict__ X, const float* __restrict__ dv,
                       u16* __restrict__ Xst) {
    __shared__ u16 tT[64 * 66];
    const int tid = threadIdx.x;
    const int r0 = blockIdx.y * 64;
    const int c0 = blockIdx.x * 64;
    const int lr = tid >> 4;
    const int lc = (tid & 15) * 4;
#pragma unroll
    for (int i = 0; i < 4; i++) {
        const int row = r0 + lr + i * 16;
        const float s = rsqrtf(dv[row]);
        f32x4 v = *(const f32x4*)(&X[(size_t)row * F_DIM + c0 + lc]);
        tT[(lc + 0) * 66 + lr + i * 16] = f2bf(v[0] * s);
        tT[(lc + 1) * 66 + lr + i * 16] = f2bf(v[1] * s);
        tT[(lc + 2) * 66 + lr + i * 16] = f2bf(v[2] * s);
        tT[(lc + 3) * 66 + lr + i * 16] = f2bf(v[3] * s);
    }
    __syncthreads();
#pragma unroll
    for (int i = 0; i < 4; i++) {
        const int er = lr + i * 16;
        const u16 b0 = tT[er * 66 + lc + 0];
        const u16 b1 = tT[er * 66 + lc + 1];
        const u16 b2 = tT[er * 66 + lc + 2];
        const u16 b3 = tT[er * 66 + lc + 3];
        u32x2 pk; pk[0] = (u32)b0 | ((u32)b1 << 16); pk[1] = (u32)b2 | ((u32)b3 << 16);
        *(u32x2*)(&Xst[(size_t)(c0 + er) * N_NODES + r0 + lc]) = pk;
    }
}

// ---------------------------------------------------------------------------
// gemm_bt — R1 verbatim structure (64x64 tile, 256 thr, BK=32, stride-40 LDS).
// EPI 0: atomicAdd fp32 (split-K accumulate, GEMM1)
// EPI 1: fp32 out = v*rsqrt(rowScale[row]) + bias[col]  (GEMM2 final; bias is
//        the ONLY change vs R1's EPI1)
// ---------------------------------------------------------------------------
template <int EPI>
__global__ void gemm_bt(const u16* __restrict__ A, const u16* __restrict__ Bt,
                        int lda, int ldb, int kSplit,
                        float* __restrict__ outF, int ldc,
                        const float* __restrict__ rowScale,
                        const float* __restrict__ bias) {
    __shared__ u16 As[64 * 40];
    __shared__ u16 Bs[64 * 40];
    const int tid = threadIdx.x;
    const int lane = tid & 63;
    const int wave = tid >> 6;
    const int wm = wave >> 1, wn = wave & 1;
    const int row16 = lane & 15;
    const int quad = lane >> 4;

    const int row0 = blockIdx.y * 64;
    const int col0 = blockIdx.x * 64;
    const int k0 = blockIdx.z * kSplit;
    const int k1 = k0 + kSplit;

    const int sr = tid >> 2;          // 0..63
    const int sk = (tid & 3) * 8;     // 0,8,16,24

    const u16* gA = A + (size_t)(row0 + sr) * lda + sk;
    const u16* gB = Bt + (size_t)(col0 + sr) * ldb + sk;

    f32x4 acc[2][2] = {};

    for (int k = k0; k < k1; k += 32) {
        u32x4 va = *(const u32x4*)(gA + k);
        u32x4 vb = *(const u32x4*)(gB + k);
        *(u32x4*)(&As[sr * 40 + sk]) = va;
        *(u32x4*)(&Bs[sr * 40 + sk]) = vb;
        __syncthreads();
        bf16x8 af[2], bfr[2];
#pragma unroll
        for (int t = 0; t < 2; t++) {
            af[t]  = *(const bf16x8*)(&As[(wm * 32 + t * 16 + row16) * 40 + quad * 8]);
            bfr[t] = *(const bf16x8*)(&Bs[(wn * 32 + t * 16 + row16) * 40 + quad * 8]);
        }
#pragma unroll
        for (int tm = 0; tm < 2; tm++)
#pragma unroll
            for (int tn = 0; tn < 2; tn++)
                acc[tm][tn] = __builtin_amdgcn_mfma_f32_16x16x32_bf16(
                    af[tm], bfr[tn], acc[tm][tn], 0, 0, 0);
        __syncthreads();
    }

#pragma unroll
    for (int tm = 0; tm < 2; tm++) {
#pragma unroll
        for (int tn = 0; tn < 2; tn++) {
            const int col = col0 + wn * 32 + tn * 16 + row16;
#pragma unroll
            for (int r = 0; r < 4; r++) {
                const int row = row0 + wm * 32 + tm * 16 + quad * 4 + r;
                float v = acc[tm][tn][r];
                if (EPI == 0) {
                    atomicAdd(&outF[(size_t)row * ldc + col], v);
                } else {
                    outF[(size_t)row * ldc + col] =
                        v * rsqrtf(rowScale[row]) + bias[col];
                }
            }
        }
    }
}

// ---------------------------------------------------------------------------
// gemm_we: M2t[j][e] = sum_f W[j][f] * Macc[f][e] / de[e]   (bf16 out)
// Replaces R1's finalize_m + prep_w + GEMM3: reads the SAME [f][e] atomic
// Macc as R1, transposes in LDS during staging (prep_x pattern), folds De^-1,
// multiplies by W (134 MF). Tile 64(j) x 64(e), grid (16,4), 256 thr, BK=64.
// ---------------------------------------------------------------------------
__global__ void gemm_we(const float* __restrict__ W, const float* __restrict__ Macc,
                        const float* __restrict__ de, u16* __restrict__ M2t) {
    __shared__ u16 As[64 * 72];   // W tile [j][f]
    __shared__ u16 Bs[64 * 72];   // (Macc/de)^T tile [e][f]
    const int tid = threadIdx.x;
    const int lane = tid & 63;
    const int wave = tid >> 6;
    const int wm = wave >> 1, wn = wave & 1;
    const int row16 = lane & 15;
    const int quad = lane >> 4;

    const int j0 = blockIdx.y * 64;     // W rows
    const int e0 = blockIdx.x * 64;     // edges

    // A staging: sr=0..63 (j), fb = 16 f per thread
    const int sr = tid >> 2;
    const int fb = (tid & 3) * 16;
    // B staging (transposing): lr = f-row 0..15 (x4), lc = 4 e per thread
    const int lr = tid >> 4;
    const int lc = (tid & 15) * 4;

    f32x4 de4 = *(const f32x4*)(&de[e0 + lc]);
    f32x4 dei = {1.f / de4[0], 1.f / de4[1], 1.f / de4[2], 1.f / de4[3]};

    f32x4 acc[2][2] = {};

    for (int k = 0; k < 256; k += 64) {
        // A tile: W[j0+sr][k+fb .. +15] fp32 -> bf16
#pragma unroll
        for (int s = 0; s < 4; s++) {
            f32x4 w = *(const f32x4*)(&W[(size_t)(j0 + sr) * 256 + k + fb + s * 4]);
            u32x2 pk;
            pk[0] = (u32)f2bf(w[0]) | ((u32)f2bf(w[1]) << 16);
            pk[1] = (u32)f2bf(w[2]) | ((u32)f2bf(w[3]) << 16);
            *(u32x2*)(&As[sr * 72 + fb + s * 4]) = pk;
        }
        // B tile: Macc[f][e] read row-wise (coalesced along e), scaled by
        // 1/de[e], written transposed -> Bs[e_local][f_local]
#pragma unroll
        for (int i = 0; i < 4; i++) {
            const int f = k + lr + i * 16;
            f32x4 m = *(const f32x4*)(&Macc[(size_t)f * N_EDGES + e0 + lc]);
            Bs[(lc + 0) * 72 + lr + i * 16] = f2bf(m[0] * dei[0]);
            Bs[(lc + 1) * 72 + lr + i * 16] = f2bf(m[1] * dei[1]);
            Bs[(lc + 2) * 72 + lr + i * 16] = f2bf(m[2] * dei[2]);
            Bs[(lc + 3) * 72 + lr + i * 16] = f2bf(m[3] * dei[3]);
        }
        __syncthreads();
#pragma unroll
        for (int ks = 0; ks < 2; ks++) {
            bf16x8 af[2], bfr[2];
#pragma unroll
            for (int i = 0; i < 2; i++)
                af[i] = *(const bf16x8*)(&As[(wm * 32 + i * 16 + row16) * 72 + ks * 32 + quad * 8]);
#pragma unroll
            for (int j = 0; j < 2; j++)
                bfr[j] = *(const bf16x8*)(&Bs[(wn * 32 + j * 16 + row16) * 72 + ks * 32 + quad * 8]);
#pragma unroll
            for (int i = 0; i < 2; i++)
#pragma unroll
                for (int j = 0; j < 2; j++)
                    acc[i][j] = __builtin_amdgcn_mfma_f32_16x16x32_bf16(
                        af[i], bfr[j], acc[i][j], 0, 0, 0);
        }
        __syncthreads();
    }

#pragma unroll
    for (int i = 0; i < 2; i++) {
#pragma unroll
        for (int j = 0; j < 2; j++) {
            const int col = e0 + wn * 32 + j * 16 + row16;
#pragma unroll
            for (int r = 0; r < 4; r++) {
                const int row = j0 + wm * 32 + i * 16 + quad * 4 + r;
                M2t[(size_t)row * N_EDGES + col] = f2bf(acc[i][j][r]);
            }
        }
    }
}

// ---------------------------------------------------------------------------
extern "C" void kernel_launch(void* const* d_in, const int* in_sizes, int n_in,
                              void* d_out, int out_size, void* d_ws, size_t ws_size,
                              hipStream_t stream) {
    (void)in_sizes; (void)n_in; (void)out_size; (void)ws_size;
    const float* X = (const float*)d_in[0];   // [8192 x 256]
    const float* H = (const float*)d_in[1];   // [8192 x 1024]
    const float* W = (const float*)d_in[2];   // [256 x 256]
    const float* b = (const float*)d_in[3];   // [256]
    float* out = (float*)d_out;               // [8192 x 256] fp32

    char* ws = (char*)d_ws;                    // R1 layout
    float* Macc = (float*)(ws);                // 1 MB   [256 x 1024] fp32
    float* dv   = (float*)(ws + 0x100000);     // 32 KB
    float* de   = (float*)(ws + 0x108000);     // 4 KB
    u16*   Hb   = (u16*)(ws + 0x110000);       // 16 MB  [8192 x 1024]
    u16*   Ht   = (u16*)(ws + 0x1110000);      // 16 MB  [1024 x 8192]
    u16*   Xst  = (u16*)(ws + 0x2110000);      // 4 MB   [256 x 8192]
    u16*   M2t  = (u16*)(ws + 0x2510000);      // 512 KB [256 x 1024]

    // zero Macc + dv + de (contiguous prefix) — R1 verbatim
    hipMemsetAsync(ws, 0, 0x109000, stream);

    prep_h<<<dim3(16, 128), 256, 0, stream>>>(H, Hb, Ht, dv, de);
    prep_x<<<dim3(4, 128), 256, 0, stream>>>(X, dv, Xst);

    // GEMM1 (R1 verbatim): Macc[f][e] += Xst * Ht^T; M=256, N=1024, K=8192,
    // split-K=8, atomic accumulate. grid (16,4,8) = 512 blocks.
    gemm_bt<0><<<dim3(16, 4, 8), 256, 0, stream>>>(
        Xst, Ht, 8192, 8192, 1024, Macc, 1024, nullptr, nullptr);

    // fold W at E-side (replaces finalize_m + prep_w + GEMM3):
    // M2t[j][e] = W (Macc/de)  -> bf16 [256 x 1024]
    gemm_we<<<dim3(16, 4), 256, 0, stream>>>(W, Macc, de, M2t);

    // GEMM2 (R1 verbatim + bias in epilogue):
    // out[n][j] = rsqrt(dv[n]) * sum_e Hb[n][e]*M2t[j][e] + b[j]
    // M=8192, N=256, K=1024. grid (4,128) = 512 blocks.
    gemm_bt<1><<<dim3(4, 128, 1), 256, 0, stream>>>(
        Hb, M2t, 1024, 1024, 1024, out, 256, dv, b);
}

// Round 7
// 153.395 us; speedup vs baseline: 1.1762x; 1.0042x over previous
//
#include <hip/hip_runtime.h>
#include <hip/hip_bf16.h>
#include <stdint.h>

typedef __attribute__((ext_vector_type(8))) short bf16x8;
typedef __attribute__((ext_vector_type(4))) float f32x4;
typedef __attribute__((ext_vector_type(4))) unsigned int u32x4;
typedef __attribute__((ext_vector_type(2))) unsigned int u32x2;
typedef unsigned short u16;
typedef unsigned int u32;

#define N_NODES 8192
#define N_EDGES 1024
#define F_DIM   256

__device__ __forceinline__ u16 f2bf(float f) {
    union { float f; u32 u; } v; v.f = f;
    u32 u = v.u;
    u = (u + 0x7FFFu + ((u >> 16) & 1u)) >> 16;   // round-nearest-even
    return (u16)u;
}

// async 16B global -> LDS (direct-to-shared DMA; m97 ladder step).
// LDS dest semantics: wave-uniform base + lane*16 (no padding possible).
__device__ __forceinline__ void async16(const u16* g, u16* l) {
    __builtin_amdgcn_global_load_lds(
        (const __attribute__((address_space(1))) u32*)(const void*)g,
        (__attribute__((address_space(3))) u32*)(void*)l, 16, 0, 0);
}

// ---------------------------------------------------------------------------
// prep_h — R1/R6 verbatim.
// One pass over H [8192 x 1024] fp32:
//   - Hb [8192 x 1024] bf16 (row-major, A-operand of GEMM2)
//   - Ht [1024 x 8192] bf16 (transposed via LDS, Bt-operand of GEMM1)
//   - dv[8192] row sums, de[1024] col sums (exact: sums of 0/1)
// ---------------------------------------------------------------------------
__global__ void prep_h(const float* __restrict__ H, u16* __restrict__ Hb,
                       u16* __restrict__ Ht, float* __restrict__ dv,
                       float* __restrict__ de) {
    __shared__ u16 tT[64 * 66];
    __shared__ float dv_s[64];
    __shared__ float de_s[64];
    const int tid = threadIdx.x;
    if (tid < 64) { dv_s[tid] = 0.f; de_s[tid] = 0.f; }
    __syncthreads();
    const int r0 = blockIdx.y * 64;
    const int c0 = blockIdx.x * 64;
    const int lr = tid >> 4;
    const int lc = (tid & 15) * 4;
    float cs0 = 0.f, cs1 = 0.f, cs2 = 0.f, cs3 = 0.f;
#pragma unroll
    for (int i = 0; i < 4; i++) {
        const int row = r0 + lr + i * 16;
        f32x4 v = *(const f32x4*)(&H[(size_t)row * N_EDGES + c0 + lc]);
        atomicAdd(&dv_s[lr + i * 16], v[0] + v[1] + v[2] + v[3]);
        cs0 += v[0]; cs1 += v[1]; cs2 += v[2]; cs3 += v[3];
        const u16 b0 = f2bf(v[0]), b1 = f2bf(v[1]), b2 = f2bf(v[2]), b3 = f2bf(v[3]);
        u32x2 pk; pk[0] = (u32)b0 | ((u32)b1 << 16); pk[1] = (u32)b2 | ((u32)b3 << 16);
        *(u32x2*)(&Hb[(size_t)row * N_EDGES + c0 + lc]) = pk;
        tT[(lc + 0) * 66 + lr + i * 16] = b0;
        tT[(lc + 1) * 66 + lr + i * 16] = b1;
        tT[(lc + 2) * 66 + lr + i * 16] = b2;
        tT[(lc + 3) * 66 + lr + i * 16] = b3;
    }
    atomicAdd(&de_s[lc + 0], cs0);
    atomicAdd(&de_s[lc + 1], cs1);
    atomicAdd(&de_s[lc + 2], cs2);
    atomicAdd(&de_s[lc + 3], cs3);
    __syncthreads();
    if (tid < 64) {
        atomicAdd(&dv[r0 + tid], dv_s[tid]);
        atomicAdd(&de[c0 + tid], de_s[tid]);
    }
#pragma unroll
    for (int i = 0; i < 4; i++) {
        const int er = lr + i * 16;
        const u16 b0 = tT[er * 66 + lc + 0];
        const u16 b1 = tT[er * 66 + lc + 1];
        const u16 b2 = tT[er * 66 + lc + 2];
        const u16 b3 = tT[er * 66 + lc + 3];
        u32x2 pk; pk[0] = (u32)b0 | ((u32)b1 << 16); pk[1] = (u32)b2 | ((u32)b3 << 16);
        *(u32x2*)(&Ht[(size_t)(c0 + er) * N_NODES + r0 + lc]) = pk;
    }
}

// ---------------------------------------------------------------------------
// prep_x — R1/R6 verbatim. Xst[f][n] = bf16(X[n][f]*rsqrt(dv[n])) [256 x 8192]
// ---------------------------------------------------------------------------
__global__ void prep_x(const float* __restrict__ X, const float* __restrict__ dv,
                       u16* __restrict__ Xst) {
    __shared__ u16 tT[64 * 66];
    const int tid = threadIdx.x;
    const int r0 = blockIdx.y * 64;
    const int c0 = blockIdx.x * 64;
    const int lr = tid >> 4;
    const int lc = (tid & 15) * 4;
#pragma unroll
    for (int i = 0; i < 4; i++) {
        const int row = r0 + lr + i * 16;
        const float s = rsqrtf(dv[row]);
        f32x4 v = *(const f32x4*)(&X[(size_t)row * F_DIM + c0 + lc]);
        tT[(lc + 0) * 66 + lr + i * 16] = f2bf(v[0] * s);
        tT[(lc + 1) * 66 + lr + i * 16] = f2bf(v[1] * s);
        tT[(lc + 2) * 66 + lr + i * 16] = f2bf(v[2] * s);
        tT[(lc + 3) * 66 + lr + i * 16] = f2bf(v[3] * s);
    }
    __syncthreads();
#pragma unroll
    for (int i = 0; i < 4; i++) {
        const int er = lr + i * 16;
        const u16 b0 = tT[er * 66 + lc + 0];
        const u16 b1 = tT[er * 66 + lc + 1];
        const u16 b2 = tT[er * 66 + lc + 2];
        const u16 b3 = tT[er * 66 + lc + 3];
        u32x2 pk; pk[0] = (u32)b0 | ((u32)b1 << 16); pk[1] = (u32)b2 | ((u32)b3 << 16);
        *(u32x2*)(&Xst[(size_t)(c0 + er) * N_NODES + r0 + lc]) = pk;
    }
}

// ---------------------------------------------------------------------------
// gemm_bt — ONE change vs R6: staging via global_load_lds width=16 (m97
// ladder step, 517->874 TF on the reference GEMM). BK=64, unpadded LDS
// (64 rows x 64 u16 = 128 B rows) as the builtin requires contiguous
// lane-order placement. Fragments/epilogues/grids unchanged.
// Per wave, per operand, per k-tile: 2 async instrs (8 rows x 128 B each);
// lane -> row = lane/8, col = (lane%8)*8 u16.
// EPI 0: atomicAdd fp32 (split-K accumulate, GEMM1)
// EPI 1: fp32 out = v*rsqrt(rowScale[row]) + bias[col]  (GEMM2 final)
// ---------------------------------------------------------------------------
template <int EPI>
__global__ void gemm_bt(const u16* __restrict__ A, const u16* __restrict__ Bt,
                        int lda, int ldb, int kSplit,
                        float* __restrict__ outF, int ldc,
                        const float* __restrict__ rowScale,
                        const float* __restrict__ bias) {
    __shared__ __align__(16) u16 As[64 * 64];
    __shared__ __align__(16) u16 Bs[64 * 64];
    const int tid = threadIdx.x;
    const int lane = tid & 63;
    const int wave = tid >> 6;          // 0..3
    const int wm = wave >> 1, wn = wave & 1;
    const int row16 = lane & 15;
    const int quad = lane >> 4;

    const int row0 = blockIdx.y * 64;
    const int col0 = blockIdx.x * 64;
    const int k0 = blockIdx.z * kSplit;
    const int k1 = k0 + kSplit;

    // async staging geometry (per 8-row instruction)
    const int srow = lane >> 3;         // 0..7
    const int scol = (lane & 7) * 8;    // u16 units

    const u16* gA0 = A + (size_t)(row0 + wave * 16 + srow) * lda + scol;
    const u16* gB0 = Bt + (size_t)(col0 + wave * 16 + srow) * ldb + scol;
    const size_t rstep8A = (size_t)8 * lda;
    const size_t rstep8B = (size_t)8 * ldb;
    u16* lA0 = &As[(wave * 16) * 64];
    u16* lB0 = &Bs[(wave * 16) * 64];

    f32x4 acc[2][2] = {};

    for (int k = k0; k < k1; k += 64) {
        async16(gA0 + k, lA0);
        async16(gA0 + k + rstep8A, lA0 + 8 * 64);
        async16(gB0 + k, lB0);
        async16(gB0 + k + rstep8B, lB0 + 8 * 64);
        __syncthreads();                 // compiler waits vmcnt for lds-loads
#pragma unroll
        for (int ks = 0; ks < 2; ks++) {
            bf16x8 af[2], bfr[2];
#pragma unroll
            for (int t = 0; t < 2; t++) {
                af[t]  = *(const bf16x8*)(&As[(wm * 32 + t * 16 + row16) * 64 + ks * 32 + quad * 8]);
                bfr[t] = *(const bf16x8*)(&Bs[(wn * 32 + t * 16 + row16) * 64 + ks * 32 + quad * 8]);
            }
#pragma unroll
            for (int tm = 0; tm < 2; tm++)
#pragma unroll
                for (int tn = 0; tn < 2; tn++)
                    acc[tm][tn] = __builtin_amdgcn_mfma_f32_16x16x32_bf16(
                        af[tm], bfr[tn], acc[tm][tn], 0, 0, 0);
        }
        __syncthreads();
    }

#pragma unroll
    for (int tm = 0; tm < 2; tm++) {
#pragma unroll
        for (int tn = 0; tn < 2; tn++) {
            const int col = col0 + wn * 32 + tn * 16 + row16;
#pragma unroll
            for (int r = 0; r < 4; r++) {
                const int row = row0 + wm * 32 + tm * 16 + quad * 4 + r;
                float v = acc[tm][tn][r];
                if (EPI == 0) {
                    atomicAdd(&outF[(size_t)row * ldc + col], v);
                } else {
                    outF[(size_t)row * ldc + col] =
                        v * rsqrtf(rowScale[row]) + bias[col];
                }
            }
        }
    }
}

// ---------------------------------------------------------------------------
// gemm_we — R6 verbatim. M2t[j][e] = sum_f W[j][f] * Macc[f][e] / de[e] (bf16)
// ---------------------------------------------------------------------------
__global__ void gemm_we(const float* __restrict__ W, const float* __restrict__ Macc,
                        const float* __restrict__ de, u16* __restrict__ M2t) {
    __shared__ u16 As[64 * 72];
    __shared__ u16 Bs[64 * 72];
    const int tid = threadIdx.x;
    const int lane = tid & 63;
    const int wave = tid >> 6;
    const int wm = wave >> 1, wn = wave & 1;
    const int row16 = lane & 15;
    const int quad = lane >> 4;

    const int j0 = blockIdx.y * 64;
    const int e0 = blockIdx.x * 64;

    const int sr = tid >> 2;
    const int fb = (tid & 3) * 16;
    const int lr = tid >> 4;
    const int lc = (tid & 15) * 4;

    f32x4 de4 = *(const f32x4*)(&de[e0 + lc]);
    f32x4 dei = {1.f / de4[0], 1.f / de4[1], 1.f / de4[2], 1.f / de4[3]};

    f32x4 acc[2][2] = {};

    for (int k = 0; k < 256; k += 64) {
#pragma unroll
        for (int s = 0; s < 4; s++) {
            f32x4 w = *(const f32x4*)(&W[(size_t)(j0 + sr) * 256 + k + fb + s * 4]);
            u32x2 pk;
            pk[0] = (u32)f2bf(w[0]) | ((u32)f2bf(w[1]) << 16);
            pk[1] = (u32)f2bf(w[2]) | ((u32)f2bf(w[3]) << 16);
            *(u32x2*)(&As[sr * 72 + fb + s * 4]) = pk;
        }
#pragma unroll
        for (int i = 0; i < 4; i++) {
            const int f = k + lr + i * 16;
            f32x4 m = *(const f32x4*)(&Macc[(size_t)f * N_EDGES + e0 + lc]);
            Bs[(lc + 0) * 72 + lr + i * 16] = f2bf(m[0] * dei[0]);
            Bs[(lc + 1) * 72 + lr + i * 16] = f2bf(m[1] * dei[1]);
            Bs[(lc + 2) * 72 + lr + i * 16] = f2bf(m[2] * dei[2]);
            Bs[(lc + 3) * 72 + lr + i * 16] = f2bf(m[3] * dei[3]);
        }
        __syncthreads();
#pragma unroll
        for (int ks = 0; ks < 2; ks++) {
            bf16x8 af[2], bfr[2];
#pragma unroll
            for (int i = 0; i < 2; i++)
                af[i] = *(const bf16x8*)(&As[(wm * 32 + i * 16 + row16) * 72 + ks * 32 + quad * 8]);
#pragma unroll
            for (int j = 0; j < 2; j++)
                bfr[j] = *(const bf16x8*)(&Bs[(wn * 32 + j * 16 + row16) * 72 + ks * 32 + quad * 8]);
#pragma unroll
            for (int i = 0; i < 2; i++)
#pragma unroll
                for (int j = 0; j < 2; j++)
                    acc[i][j] = __builtin_amdgcn_mfma_f32_16x16x32_bf16(
                        af[i], bfr[j], acc[i][j], 0, 0, 0);
        }
        __syncthreads();
    }

#pragma unroll
    for (int i = 0; i < 2; i++) {
#pragma unroll
        for (int j = 0; j < 2; j++) {
            const int col = e0 + wn * 32 + j * 16 + row16;
#pragma unroll
            for (int r = 0; r < 4; r++) {
                const int row = j0 + wm * 32 + i * 16 + quad * 4 + r;
                M2t[(size_t)row * N_EDGES + col] = f2bf(acc[i][j][r]);
            }
        }
    }
}

// ---------------------------------------------------------------------------
extern "C" void kernel_launch(void* const* d_in, const int* in_sizes, int n_in,
                              void* d_out, int out_size, void* d_ws, size_t ws_size,
                              hipStream_t stream) {
    (void)in_sizes; (void)n_in; (void)out_size; (void)ws_size;
    const float* X = (const float*)d_in[0];   // [8192 x 256]
    const float* H = (const float*)d_in[1];   // [8192 x 1024]
    const float* W = (const float*)d_in[2];   // [256 x 256]
    const float* b = (const float*)d_in[3];   // [256]
    float* out = (float*)d_out;               // [8192 x 256] fp32

    char* ws = (char*)d_ws;                    // R6 layout
    float* Macc = (float*)(ws);                // 1 MB   [256 x 1024] fp32
    float* dv   = (float*)(ws + 0x100000);     // 32 KB
    float* de   = (float*)(ws + 0x108000);     // 4 KB
    u16*   Hb   = (u16*)(ws + 0x110000);       // 16 MB  [8192 x 1024]
    u16*   Ht   = (u16*)(ws + 0x1110000);      // 16 MB  [1024 x 8192]
    u16*   Xst  = (u16*)(ws + 0x2110000);      // 4 MB   [256 x 8192]
    u16*   M2t  = (u16*)(ws + 0x2510000);      // 512 KB [256 x 1024]

    hipMemsetAsync(ws, 0, 0x109000, stream);   // Macc + dv + de

    prep_h<<<dim3(16, 128), 256, 0, stream>>>(H, Hb, Ht, dv, de);
    prep_x<<<dim3(4, 128), 256, 0, stream>>>(X, dv, Xst);

    // GEMM1: Macc[f][e] += Xst * Ht^T; M=256, N=1024, K=8192, split-K=8.
    gemm_bt<0><<<dim3(16, 4, 8), 256, 0, stream>>>(
        Xst, Ht, 8192, 8192, 1024, Macc, 1024, nullptr, nullptr);

    // fold W at E-side: M2t[j][e] = W (Macc/de) -> bf16 [256 x 1024]
    gemm_we<<<dim3(16, 4), 256, 0, stream>>>(W, Macc, de, M2t);

    // GEMM2: out[n][j] = rsqrt(dv[n]) * sum_e Hb[n][e]*M2t[j][e] + b[j]
    gemm_bt<1><<<dim3(4, 128, 1), 256, 0, stream>>>(
        Hb, M2t, 1024, 1024, 1024, out, 256, dv, b);
}